// Round 1
// baseline (503.449 us; speedup 1.0000x reference)
//
#include <hip/hip_runtime.h>
#include <hip/hip_bf16.h>
#include <math.h>

#define BN 256
#define NN 2048
#define CC 64

// workspace float offsets
#define WS_SUMQ 0                   // B*64
#define WS_SUMM (BN * 64)           // B
#define WS_V    (WS_SUMM + BN)      // B*64
#define WS_S    (WS_V + BN * 64)    // B*8
#define WS_KQ   (WS_S + BN * 8)     // B*512  kq[b][c][h]
#define WS_MASK (WS_KQ + BN * 512)  // B*2048 compact mask column
#define WS_ZERO_FLOATS WS_KQ        // zero the accumulator region only

typedef __bf16 bf16x8 __attribute__((ext_vector_type(8)));
typedef float f32x4 __attribute__((ext_vector_type(4)));

// ---------------- K1: masked pool over N (partial, split 4 ways) ----------------
__global__ __launch_bounds__(256) void k_pool(const float* __restrict__ qd,
                                              const float* __restrict__ qm,
                                              float* __restrict__ ws) {
    const int b = blockIdx.x >> 2, chunk = blockIdx.x & 3;
    const int tid = threadIdx.x;
    const int r = tid >> 4, c4 = tid & 15;
    const float* qb = qd + (size_t)b * NN * CC;
    const float* mb = qm + (size_t)b * NN * CC;
    float* wmask = ws + WS_MASK + b * NN;

    float4 acc = {0.f, 0.f, 0.f, 0.f};
    float msum = 0.f;
#pragma unroll 4
    for (int i = 0; i < 32; ++i) {
        const int n = chunk * 512 + i * 16 + r;
        const float m = mb[(size_t)n * CC];  // channel-0 of broadcast mask
        const float4 q4 = *(const float4*)(qb + (size_t)n * CC + c4 * 4);
        acc.x += m * q4.x; acc.y += m * q4.y; acc.z += m * q4.z; acc.w += m * q4.w;
        msum += m;
        if (c4 == 0) wmask[n] = m;
    }

    __shared__ float red[16][64];
    __shared__ float wsum[4];
    red[r][c4 * 4 + 0] = acc.x; red[r][c4 * 4 + 1] = acc.y;
    red[r][c4 * 4 + 2] = acc.z; red[r][c4 * 4 + 3] = acc.w;
    // wave reduce the (x16 duplicated) mask sum
    for (int off = 32; off > 0; off >>= 1) msum += __shfl_down(msum, off, 64);
    if ((tid & 63) == 0) wsum[tid >> 6] = msum;
    __syncthreads();
    if (tid < 64) {
        float s = 0.f;
#pragma unroll
        for (int rr = 0; rr < 16; ++rr) s += red[rr][tid];
        atomicAdd(ws + WS_SUMQ + b * 64 + tid, s);
    }
    if (tid == 0) {
        atomicAdd(ws + WS_SUMM + b,
                  (wsum[0] + wsum[1] + wsum[2] + wsum[3]) * (1.f / 16.f));
    }
}

// ---------------- K2: q = (q_avg @ q_w)*scale; kq[c][h] = k_w[c,:]·q[h,:] ----------------
__global__ __launch_bounds__(64) void k_qproj(const float* __restrict__ qw,
                                              const float* __restrict__ kw,
                                              float* __restrict__ ws) {
    const int b = blockIdx.x, t = threadIdx.x;
    __shared__ float qa[64], ql[64];
    const float denom = ws[WS_SUMM + b] + 1e-10f;
    qa[t] = ws[WS_SUMQ + b * 64 + t] / denom;
    __syncthreads();
    float s = 0.f;
#pragma unroll
    for (int c = 0; c < 64; ++c) s += qa[c] * qw[c * 64 + t];
    ql[t] = s * 0.35355339059327373f;  // KD^-0.5, KD=8
    __syncthreads();
#pragma unroll
    for (int h = 0; h < 8; ++h) {
        float s2 = 0.f;
#pragma unroll
        for (int d = 0; d < 8; ++d) s2 += kw[t * 8 + d] * ql[h * 8 + d];
        ws[WS_KQ + b * 512 + t * 8 + h] = s2;
    }
}

// ---------------- K3: attention partials  S[h] += p, V[h][d] += p*v  ----------------
__global__ __launch_bounds__(256) void k_attn(const float* __restrict__ md,
                                              const float* __restrict__ vw,
                                              float* __restrict__ ws) {
    const int b = blockIdx.x >> 2, chunk = blockIdx.x & 3;
    const int tid = threadIdx.x;
    __shared__ float wkv[64][16];  // [c][0..7]=kq, [c][8..15]=vw
    for (int i = tid; i < 512; i += 256) {
        const int c = i >> 3, d = i & 7;
        wkv[c][d] = ws[WS_KQ + b * 512 + i];
        wkv[c][8 + d] = vw[i];
    }
    __syncthreads();

    const int n0 = chunk * 512 + tid, n1 = n0 + 256;
    float la0[8], va0[8], la1[8], va1[8];
#pragma unroll
    for (int h = 0; h < 8; ++h) { la0[h] = va0[h] = la1[h] = va1[h] = 0.f; }
    const float4* r0 = (const float4*)(md + ((size_t)b * NN + n0) * CC);
    const float4* r1 = (const float4*)(md + ((size_t)b * NN + n1) * CC);
#pragma unroll 4
    for (int c4 = 0; c4 < 16; ++c4) {
        const float4 m0 = r0[c4], m1 = r1[c4];
        const float m0a[4] = {m0.x, m0.y, m0.z, m0.w};
        const float m1a[4] = {m1.x, m1.y, m1.z, m1.w};
#pragma unroll
        for (int j = 0; j < 4; ++j) {
            const int c = c4 * 4 + j;
            const float4* wr = (const float4*)wkv[c];  // broadcast reads
            const float4 wa = wr[0], wb = wr[1], wc = wr[2], wd = wr[3];
            const float x0 = m0a[j], x1 = m1a[j];
            la0[0] += x0 * wa.x; la0[1] += x0 * wa.y; la0[2] += x0 * wa.z; la0[3] += x0 * wa.w;
            la0[4] += x0 * wb.x; la0[5] += x0 * wb.y; la0[6] += x0 * wb.z; la0[7] += x0 * wb.w;
            va0[0] += x0 * wc.x; va0[1] += x0 * wc.y; va0[2] += x0 * wc.z; va0[3] += x0 * wc.w;
            va0[4] += x0 * wd.x; va0[5] += x0 * wd.y; va0[6] += x0 * wd.z; va0[7] += x0 * wd.w;
            la1[0] += x1 * wa.x; la1[1] += x1 * wa.y; la1[2] += x1 * wa.z; la1[3] += x1 * wa.w;
            la1[4] += x1 * wb.x; la1[5] += x1 * wb.y; la1[6] += x1 * wb.z; la1[7] += x1 * wb.w;
            va1[0] += x1 * wc.x; va1[1] += x1 * wc.y; va1[2] += x1 * wc.z; va1[3] += x1 * wc.w;
            va1[4] += x1 * wd.x; va1[5] += x1 * wd.y; va1[6] += x1 * wd.z; va1[7] += x1 * wd.w;
        }
    }
    const float mk0 = ws[WS_MASK + b * NN + n0];
    const float mk1 = ws[WS_MASK + b * NN + n1];

    __shared__ float P[512][9];   // +1 pad: write banks = 9*tid mod 32 (gcd 1 -> 2-way, free)
    __shared__ float Vv[512][9];
#pragma unroll
    for (int h = 0; h < 8; ++h) {
        P[tid][h] = mk0 * __expf(la0[h]);       // masked rows -> exactly 0, same as exp(l-1e9)
        P[tid + 256][h] = mk1 * __expf(la1[h]);
    }
#pragma unroll
    for (int d = 0; d < 8; ++d) {
        Vv[tid][d] = va0[d];
        Vv[tid + 256][d] = va1[d];
    }
    __syncthreads();
    const int w = tid >> 6, lane = tid & 63, h = lane >> 3, d = lane & 7;
    float acc = 0.f, sacc = 0.f;
    for (int n = w * 128; n < w * 128 + 128; ++n) {
        const float p = P[n][h];
        acc += p * Vv[n][d];
        sacc += p;
    }
    atomicAdd(ws + WS_V + b * 64 + h * 8 + d, acc);
    if (d == 0) atomicAdd(ws + WS_S + b * 8 + h, sacc);
}

// ---------------- K4: gate = sigmoid(q_data@Gw + gb); out = (gate*wavg)@Ow + ob ----------------
// MFMA 16x16x32 bf16. Layouts (HW-verified, guide §3):
//   A[m=lane&15][k=(lane>>4)*8+j], B[k=(lane>>4)*8+j][n=lane&15], D[row=(lane>>4)*4+r][col=lane&15]
__global__ __launch_bounds__(256) void k_out(const float* __restrict__ qd,
                                             const float* __restrict__ ow,
                                             const float* __restrict__ obias,
                                             const float* __restrict__ gw,
                                             const float* __restrict__ gb,
                                             const float* __restrict__ ws,
                                             float* __restrict__ out) {
    const int b = blockIdx.x >> 3, chunk = blockIdx.x & 7;
    const int tid = threadIdx.x;
    const int w = tid >> 6, lane = tid & 63, q16 = lane >> 4, c16 = lane & 15;

    // Per-wave constant B-fragments: Gw (gating weights) and W2 = wavg ⊙ Ow
    bf16x8 gwf[2][4], w2f[2][4];
    float gbv[4], obv[4];
#pragma unroll
    for (int kc = 0; kc < 2; ++kc) {
        const int k0 = kc * 32 + q16 * 8;
        const float inv_s = 1.f / ws[WS_S + b * 8 + (k0 >> 3)];  // same h for all 8 j's
#pragma unroll
        for (int t = 0; t < 4; ++t) {
            const int n = t * 16 + c16;
            bf16x8 gf, wf;
#pragma unroll
            for (int j = 0; j < 8; ++j) {
                gf[j] = (__bf16)gw[(size_t)(k0 + j) * 64 + n];
                wf[j] = (__bf16)(ws[WS_V + b * 64 + k0 + j] * inv_s *
                                 ow[(size_t)(k0 + j) * 64 + n]);
            }
            gwf[kc][t] = gf;
            w2f[kc][t] = wf;
        }
    }
#pragma unroll
    for (int t = 0; t < 4; ++t) {
        gbv[t] = gb[t * 16 + c16];
        obv[t] = obias[t * 16 + c16];
    }

    // C-layout -> A-layout transpose buffer; row padded 64->72 bf16 (144B) to spread banks
    __shared__ __align__(16) __bf16 gl[4][16][72];

    for (int s = 0; s < 4; ++s) {
        const size_t row0 = (size_t)b * NN + chunk * 256 + s * 64 + w * 16;
        const float* arow = qd + (row0 + c16) * CC;
        bf16x8 af[2];
#pragma unroll
        for (int kc = 0; kc < 2; ++kc) {
            const float4 x0 = *(const float4*)(arow + kc * 32 + q16 * 8);
            const float4 x1 = *(const float4*)(arow + kc * 32 + q16 * 8 + 4);
            bf16x8 a;
            a[0] = (__bf16)x0.x; a[1] = (__bf16)x0.y; a[2] = (__bf16)x0.z; a[3] = (__bf16)x0.w;
            a[4] = (__bf16)x1.x; a[5] = (__bf16)x1.y; a[6] = (__bf16)x1.z; a[7] = (__bf16)x1.w;
            af[kc] = a;
        }
        f32x4 accg[4] = {{0.f, 0.f, 0.f, 0.f}, {0.f, 0.f, 0.f, 0.f},
                         {0.f, 0.f, 0.f, 0.f}, {0.f, 0.f, 0.f, 0.f}};
#pragma unroll
        for (int kc = 0; kc < 2; ++kc)
#pragma unroll
            for (int t = 0; t < 4; ++t)
                accg[t] = __builtin_amdgcn_mfma_f32_16x16x32_bf16(af[kc], gwf[kc][t],
                                                                  accg[t], 0, 0, 0);
        // sigmoid + stash in A-operand order
#pragma unroll
        for (int t = 0; t < 4; ++t)
#pragma unroll
            for (int r2 = 0; r2 < 4; ++r2) {
                const float x = accg[t][r2] + gbv[t];
                const float g = 1.f / (1.f + __expf(-x));
                gl[w][q16 * 4 + r2][t * 16 + c16] = (__bf16)g;
            }
        __syncthreads();
        bf16x8 a2[2];
#pragma unroll
        for (int kc = 0; kc < 2; ++kc)
            a2[kc] = *(const bf16x8*)&gl[w][c16][kc * 32 + q16 * 8];
        f32x4 acco[4] = {{0.f, 0.f, 0.f, 0.f}, {0.f, 0.f, 0.f, 0.f},
                         {0.f, 0.f, 0.f, 0.f}, {0.f, 0.f, 0.f, 0.f}};
#pragma unroll
        for (int kc = 0; kc < 2; ++kc)
#pragma unroll
            for (int t = 0; t < 4; ++t)
                acco[t] = __builtin_amdgcn_mfma_f32_16x16x32_bf16(a2[kc], w2f[kc][t],
                                                                  acco[t], 0, 0, 0);
        __syncthreads();
        float* orow = out + row0 * 64;
#pragma unroll
        for (int t = 0; t < 4; ++t)
#pragma unroll
            for (int r2 = 0; r2 < 4; ++r2)
                orow[(size_t)(q16 * 4 + r2) * 64 + t * 16 + c16] = acco[t][r2] + obv[t];
    }
}

extern "C" void kernel_launch(void* const* d_in, const int* in_sizes, int n_in,
                              void* d_out, int out_size, void* d_ws, size_t ws_size,
                              hipStream_t stream) {
    const float* q_data = (const float*)d_in[0];
    const float* m_data = (const float*)d_in[1];
    const float* q_mask = (const float*)d_in[2];
    // d_in[3] = bias, ignored by the forward (AF2 quirk)
    const float* q_w = (const float*)d_in[4];
    const float* k_w = (const float*)d_in[5];
    const float* v_w = (const float*)d_in[6];
    const float* o_w = (const float*)d_in[7];
    const float* o_b = (const float*)d_in[8];
    const float* g_w = (const float*)d_in[9];
    const float* g_b = (const float*)d_in[10];
    float* out = (float*)d_out;
    float* ws = (float*)d_ws;

    hipMemsetAsync(ws, 0, (size_t)WS_ZERO_FLOATS * sizeof(float), stream);
    hipLaunchKernelGGL(k_pool, dim3(BN * 4), dim3(256), 0, stream, q_data, q_mask, ws);
    hipLaunchKernelGGL(k_qproj, dim3(BN), dim3(64), 0, stream, q_w, k_w, ws);
    hipLaunchKernelGGL(k_attn, dim3(BN * 4), dim3(256), 0, stream, m_data, v_w, ws);
    hipLaunchKernelGGL(k_out, dim3(BN * 8), dim3(256), 0, stream, q_data, o_w, o_b,
                       g_w, g_b, ws, out);
}

// Round 2
// 485.618 us; speedup vs baseline: 1.0367x; 1.0367x over previous
//
#include <hip/hip_runtime.h>
#include <hip/hip_bf16.h>
#include <math.h>

#define BN 256
#define NN 2048
#define CC 64

// workspace float offsets
#define WS_SUMQ 0                   // B*64
#define WS_SUMM (BN * 64)           // B
#define WS_V    (WS_SUMM + BN)      // B*64
#define WS_S    (WS_V + BN * 64)    // B*8
#define WS_KQ   (WS_S + BN * 8)     // B*512  kq[b][c][h]
#define WS_MASK (WS_KQ + BN * 512)  // B*2048 compact mask column
#define WS_ZERO_FLOATS WS_KQ        // zero the accumulator region only

typedef __bf16 bf16x8 __attribute__((ext_vector_type(8)));
typedef float f32x4 __attribute__((ext_vector_type(4)));

// ---------------- K1: masked pool over N (partial, split 4 ways) ----------------
__global__ __launch_bounds__(256) void k_pool(const float* __restrict__ qd,
                                              const float* __restrict__ qm,
                                              float* __restrict__ ws) {
    const int b = blockIdx.x >> 2, chunk = blockIdx.x & 3;
    const int tid = threadIdx.x;
    const int r = tid >> 4, c4 = tid & 15;
    const float* qb = qd + (size_t)b * NN * CC;
    const float* mb = qm + (size_t)b * NN * CC;
    float* wmask = ws + WS_MASK + b * NN;

    float4 acc = {0.f, 0.f, 0.f, 0.f};
    float msum = 0.f;
#pragma unroll 4
    for (int i = 0; i < 32; ++i) {
        const int n = chunk * 512 + i * 16 + r;
        const float m = mb[(size_t)n * CC];  // channel-0 of broadcast mask
        const float4 q4 = *(const float4*)(qb + (size_t)n * CC + c4 * 4);
        acc.x += m * q4.x; acc.y += m * q4.y; acc.z += m * q4.z; acc.w += m * q4.w;
        msum += m;
        if (c4 == 0) wmask[n] = m;
    }

    __shared__ float red[16][64];
    __shared__ float wsum[4];
    red[r][c4 * 4 + 0] = acc.x; red[r][c4 * 4 + 1] = acc.y;
    red[r][c4 * 4 + 2] = acc.z; red[r][c4 * 4 + 3] = acc.w;
    // wave reduce the (x16 duplicated) mask sum
    for (int off = 32; off > 0; off >>= 1) msum += __shfl_down(msum, off, 64);
    if ((tid & 63) == 0) wsum[tid >> 6] = msum;
    __syncthreads();
    if (tid < 64) {
        float s = 0.f;
#pragma unroll
        for (int rr = 0; rr < 16; ++rr) s += red[rr][tid];
        atomicAdd(ws + WS_SUMQ + b * 64 + tid, s);
    }
    if (tid == 0) {
        atomicAdd(ws + WS_SUMM + b,
                  (wsum[0] + wsum[1] + wsum[2] + wsum[3]) * (1.f / 16.f));
    }
}

// ---------------- K2: q = (q_avg @ q_w)*scale; kq[c][h] = k_w[c,:]·q[h,:] ----------------
__global__ __launch_bounds__(64) void k_qproj(const float* __restrict__ qw,
                                              const float* __restrict__ kw,
                                              float* __restrict__ ws) {
    const int b = blockIdx.x, t = threadIdx.x;
    __shared__ float qa[64], ql[64];
    const float denom = ws[WS_SUMM + b] + 1e-10f;
    qa[t] = ws[WS_SUMQ + b * 64 + t] / denom;
    __syncthreads();
    float s = 0.f;
#pragma unroll
    for (int c = 0; c < 64; ++c) s += qa[c] * qw[c * 64 + t];
    ql[t] = s * 0.35355339059327373f;  // KD^-0.5, KD=8
    __syncthreads();
#pragma unroll
    for (int h = 0; h < 8; ++h) {
        float s2 = 0.f;
#pragma unroll
        for (int d = 0; d < 8; ++d) s2 += kw[t * 8 + d] * ql[h * 8 + d];
        ws[WS_KQ + b * 512 + t * 8 + h] = s2;
    }
}

// ---------------- K3: attention partials  S[h] += p, V[h][d] += p*v  ----------------
__global__ __launch_bounds__(256) void k_attn(const float* __restrict__ md,
                                              const float* __restrict__ vw,
                                              float* __restrict__ ws) {
    const int b = blockIdx.x >> 2, chunk = blockIdx.x & 3;
    const int tid = threadIdx.x;
    __shared__ float wkv[64][16];  // [c][0..7]=kq, [c][8..15]=vw
    for (int i = tid; i < 512; i += 256) {
        const int c = i >> 3, d = i & 7;
        wkv[c][d] = ws[WS_KQ + b * 512 + i];
        wkv[c][8 + d] = vw[i];
    }
    __syncthreads();

    const int n0 = chunk * 512 + tid, n1 = n0 + 256;
    float la0[8], va0[8], la1[8], va1[8];
#pragma unroll
    for (int h = 0; h < 8; ++h) { la0[h] = va0[h] = la1[h] = va1[h] = 0.f; }
    const float4* r0 = (const float4*)(md + ((size_t)b * NN + n0) * CC);
    const float4* r1 = (const float4*)(md + ((size_t)b * NN + n1) * CC);
#pragma unroll 4
    for (int c4 = 0; c4 < 16; ++c4) {
        const float4 m0 = r0[c4], m1 = r1[c4];
        const float m0a[4] = {m0.x, m0.y, m0.z, m0.w};
        const float m1a[4] = {m1.x, m1.y, m1.z, m1.w};
#pragma unroll
        for (int j = 0; j < 4; ++j) {
            const int c = c4 * 4 + j;
            const float4* wr = (const float4*)wkv[c];  // broadcast reads
            const float4 wa = wr[0], wb = wr[1], wc = wr[2], wd = wr[3];
            const float x0 = m0a[j], x1 = m1a[j];
            la0[0] += x0 * wa.x; la0[1] += x0 * wa.y; la0[2] += x0 * wa.z; la0[3] += x0 * wa.w;
            la0[4] += x0 * wb.x; la0[5] += x0 * wb.y; la0[6] += x0 * wb.z; la0[7] += x0 * wb.w;
            va0[0] += x0 * wc.x; va0[1] += x0 * wc.y; va0[2] += x0 * wc.z; va0[3] += x0 * wc.w;
            va0[4] += x0 * wd.x; va0[5] += x0 * wd.y; va0[6] += x0 * wd.z; va0[7] += x0 * wd.w;
            la1[0] += x1 * wa.x; la1[1] += x1 * wa.y; la1[2] += x1 * wa.z; la1[3] += x1 * wa.w;
            la1[4] += x1 * wb.x; la1[5] += x1 * wb.y; la1[6] += x1 * wb.z; la1[7] += x1 * wb.w;
            va1[0] += x1 * wc.x; va1[1] += x1 * wc.y; va1[2] += x1 * wc.z; va1[3] += x1 * wc.w;
            va1[4] += x1 * wd.x; va1[5] += x1 * wd.y; va1[6] += x1 * wd.z; va1[7] += x1 * wd.w;
        }
    }
    const float mk0 = ws[WS_MASK + b * NN + n0];
    const float mk1 = ws[WS_MASK + b * NN + n1];

    __shared__ float P[512][9];   // +1 pad: write banks = 9*tid mod 32 (gcd 1 -> 2-way, free)
    __shared__ float Vv[512][9];
#pragma unroll
    for (int h = 0; h < 8; ++h) {
        P[tid][h] = mk0 * __expf(la0[h]);       // masked rows -> exactly 0, same as exp(l-1e9)
        P[tid + 256][h] = mk1 * __expf(la1[h]);
    }
#pragma unroll
    for (int d = 0; d < 8; ++d) {
        Vv[tid][d] = va0[d];
        Vv[tid + 256][d] = va1[d];
    }
    __syncthreads();
    const int w = tid >> 6, lane = tid & 63, h = lane >> 3, d = lane & 7;
    float acc = 0.f, sacc = 0.f;
    for (int n = w * 128; n < w * 128 + 128; ++n) {
        const float p = P[n][h];
        acc += p * Vv[n][d];
        sacc += p;
    }
    atomicAdd(ws + WS_V + b * 64 + h * 8 + d, acc);
    if (d == 0) atomicAdd(ws + WS_S + b * 8 + h, sacc);
}

// ---------------- K4: gate = sigmoid(q_data@Gw + gb); out = (gate*wavg)@Ow + ob ----------------
// MFMA 16x16x32 bf16. Layouts (HW-verified, guide §3):
//   A[m=lane&15][k=(lane>>4)*8+j], B[k=(lane>>4)*8+j][n=lane&15], D[row=(lane>>4)*4+r][col=lane&15]
// R1: barriers removed (transpose buffer gl[w] is wave-private; LDS ops are
// in-order within a wave -> s_waitcnt lgkmcnt(0) suffices), and A-slab global
// loads are software-pipelined depth-1 so slab s+1's dwordx4s are in flight
// while slab s computes.
__global__ __launch_bounds__(256) void k_out(const float* __restrict__ qd,
                                             const float* __restrict__ ow,
                                             const float* __restrict__ obias,
                                             const float* __restrict__ gw,
                                             const float* __restrict__ gb,
                                             const float* __restrict__ ws,
                                             float* __restrict__ out) {
    const int b = blockIdx.x >> 3, chunk = blockIdx.x & 7;
    const int tid = threadIdx.x;
    const int w = tid >> 6, lane = tid & 63, q16 = lane >> 4, c16 = lane & 15;

    // Per-wave constant B-fragments: Gw (gating weights) and W2 = wavg ⊙ Ow
    bf16x8 gwf[2][4], w2f[2][4];
    float gbv[4], obv[4];
#pragma unroll
    for (int kc = 0; kc < 2; ++kc) {
        const int k0 = kc * 32 + q16 * 8;
        const float inv_s = 1.f / ws[WS_S + b * 8 + (k0 >> 3)];  // same h for all 8 j's
#pragma unroll
        for (int t = 0; t < 4; ++t) {
            const int n = t * 16 + c16;
            bf16x8 gf, wf;
#pragma unroll
            for (int j = 0; j < 8; ++j) {
                gf[j] = (__bf16)gw[(size_t)(k0 + j) * 64 + n];
                wf[j] = (__bf16)(ws[WS_V + b * 64 + k0 + j] * inv_s *
                                 ow[(size_t)(k0 + j) * 64 + n]);
            }
            gwf[kc][t] = gf;
            w2f[kc][t] = wf;
        }
    }
#pragma unroll
    for (int t = 0; t < 4; ++t) {
        gbv[t] = gb[t * 16 + c16];
        obv[t] = obias[t * 16 + c16];
    }

    // C-layout -> A-layout transpose buffer; wave-private region gl[w];
    // row padded 64->72 bf16 (144B) to spread banks
    __shared__ __align__(16) __bf16 gl[4][16][72];

    const size_t base_row = (size_t)b * NN + chunk * 256 + w * 16;

    float4 cur0, cur1, cur2, cur3, nxt0, nxt1, nxt2, nxt3;
    {
        const float* arow = qd + (base_row + c16) * CC;
        cur0 = *(const float4*)(arow + q16 * 8);
        cur1 = *(const float4*)(arow + q16 * 8 + 4);
        cur2 = *(const float4*)(arow + 32 + q16 * 8);
        cur3 = *(const float4*)(arow + 32 + q16 * 8 + 4);
    }

    for (int s = 0; s < 4; ++s) {
        if (s < 3) {  // prefetch next slab
            const float* arow = qd + (base_row + (s + 1) * 64 + c16) * CC;
            nxt0 = *(const float4*)(arow + q16 * 8);
            nxt1 = *(const float4*)(arow + q16 * 8 + 4);
            nxt2 = *(const float4*)(arow + 32 + q16 * 8);
            nxt3 = *(const float4*)(arow + 32 + q16 * 8 + 4);
        }
        bf16x8 af[2];
        {
            bf16x8 a;
            a[0] = (__bf16)cur0.x; a[1] = (__bf16)cur0.y; a[2] = (__bf16)cur0.z; a[3] = (__bf16)cur0.w;
            a[4] = (__bf16)cur1.x; a[5] = (__bf16)cur1.y; a[6] = (__bf16)cur1.z; a[7] = (__bf16)cur1.w;
            af[0] = a;
            a[0] = (__bf16)cur2.x; a[1] = (__bf16)cur2.y; a[2] = (__bf16)cur2.z; a[3] = (__bf16)cur2.w;
            a[4] = (__bf16)cur3.x; a[5] = (__bf16)cur3.y; a[6] = (__bf16)cur3.z; a[7] = (__bf16)cur3.w;
            af[1] = a;
        }
        f32x4 accg[4] = {{0.f, 0.f, 0.f, 0.f}, {0.f, 0.f, 0.f, 0.f},
                         {0.f, 0.f, 0.f, 0.f}, {0.f, 0.f, 0.f, 0.f}};
#pragma unroll
        for (int kc = 0; kc < 2; ++kc)
#pragma unroll
            for (int t = 0; t < 4; ++t)
                accg[t] = __builtin_amdgcn_mfma_f32_16x16x32_bf16(af[kc], gwf[kc][t],
                                                                  accg[t], 0, 0, 0);
        // sigmoid + stash in A-operand order (wave-private LDS region)
#pragma unroll
        for (int t = 0; t < 4; ++t)
#pragma unroll
            for (int r2 = 0; r2 < 4; ++r2) {
                const float x = accg[t][r2] + gbv[t];
                const float g = 1.f / (1.f + __expf(-x));
                gl[w][q16 * 4 + r2][t * 16 + c16] = (__bf16)g;
            }
        __asm__ volatile("s_waitcnt lgkmcnt(0)" ::: "memory");
        bf16x8 a2[2];
#pragma unroll
        for (int kc = 0; kc < 2; ++kc)
            a2[kc] = *(const bf16x8*)&gl[w][c16][kc * 32 + q16 * 8];
        f32x4 acco[4] = {{0.f, 0.f, 0.f, 0.f}, {0.f, 0.f, 0.f, 0.f},
                         {0.f, 0.f, 0.f, 0.f}, {0.f, 0.f, 0.f, 0.f}};
#pragma unroll
        for (int kc = 0; kc < 2; ++kc)
#pragma unroll
            for (int t = 0; t < 4; ++t)
                acco[t] = __builtin_amdgcn_mfma_f32_16x16x32_bf16(a2[kc], w2f[kc][t],
                                                                  acco[t], 0, 0, 0);
        __asm__ volatile("s_waitcnt lgkmcnt(0)" ::: "memory");  // reads done before next slab's writes
        float* orow = out + (base_row + s * 64) * CC;
#pragma unroll
        for (int t = 0; t < 4; ++t)
#pragma unroll
            for (int r2 = 0; r2 < 4; ++r2)
                orow[(size_t)(q16 * 4 + r2) * 64 + t * 16 + c16] = acco[t][r2] + obv[t];
        cur0 = nxt0; cur1 = nxt1; cur2 = nxt2; cur3 = nxt3;
    }
}

extern "C" void kernel_launch(void* const* d_in, const int* in_sizes, int n_in,
                              void* d_out, int out_size, void* d_ws, size_t ws_size,
                              hipStream_t stream) {
    const float* q_data = (const float*)d_in[0];
    const float* m_data = (const float*)d_in[1];
    const float* q_mask = (const float*)d_in[2];
    // d_in[3] = bias, ignored by the forward (AF2 quirk)
    const float* q_w = (const float*)d_in[4];
    const float* k_w = (const float*)d_in[5];
    const float* v_w = (const float*)d_in[6];
    const float* o_w = (const float*)d_in[7];
    const float* o_b = (const float*)d_in[8];
    const float* g_w = (const float*)d_in[9];
    const float* g_b = (const float*)d_in[10];
    float* out = (float*)d_out;
    float* ws = (float*)d_ws;

    hipMemsetAsync(ws, 0, (size_t)WS_ZERO_FLOATS * sizeof(float), stream);
    hipLaunchKernelGGL(k_pool, dim3(BN * 4), dim3(256), 0, stream, q_data, q_mask, ws);
    hipLaunchKernelGGL(k_qproj, dim3(BN), dim3(64), 0, stream, q_w, k_w, ws);
    hipLaunchKernelGGL(k_attn, dim3(BN * 4), dim3(256), 0, stream, m_data, v_w, ws);
    hipLaunchKernelGGL(k_out, dim3(BN * 8), dim3(256), 0, stream, q_data, o_w, o_b,
                       g_w, g_b, ws, out);
}